// Round 6
// baseline (258.841 us; speedup 1.0000x reference)
//
#include <hip/hip_runtime.h>

#define ROWS  16
#define GB    512     // gemm kernel block
#define PB    256     // prep kernel block
#define PAD   620     // inp row pad: (620*4B=2480B, 16B-aligned; rows 2 apart land banks {0,8,16,24} -> conflict-free)
#define AGG_STRIDE 344

// ---------------- kernel 1: neighbor node+edge aggregation (no LDS, no barriers) ----------------
// item i in [0, 16384*86): grow = i/86 (side*8192+row), cc = i%86
//   cc <  43: node-feature chunk cc  -> agg[grow][0   + 4*cc .. +3]
//   cc >= 43: edge-feature chunk     -> agg[grow][172 + 4*c  .. +3]
__global__ __launch_bounds__(PB) void prep_gather(
    const float* __restrict__ nodef,   // [200000,172]
    const float* __restrict__ edgef,   // [500000,172]
    const int*   __restrict__ s_nbr,   // [8192,32]
    const int*   __restrict__ s_eid,
    const int*   __restrict__ d_nbr,
    const int*   __restrict__ d_eid,
    float*       __restrict__ agg)     // [16384, 344]
{
    const int i    = blockIdx.x * PB + threadIdx.x;
    const int grow = i / 86, cc = i - grow * 86;
    const int side = grow >> 13, row = grow & 8191;
    const bool is_edge = cc >= 43;
    const int  c  = is_edge ? cc - 43 : cc;
    const int  dd = 4 * c;

    const int* idt = is_edge ? (side ? d_eid : s_eid)
                             : (side ? d_nbr : s_nbr);
    const float* bp = is_edge ? edgef : nodef;
    const int4* idv = (const int4*)&idt[row * 32];   // 32 ids, 16B-aligned

    float4 acc = {0.f, 0.f, 0.f, 0.f};
    #pragma unroll
    for (int b = 0; b < 4; ++b) {
        int4 q0 = idv[2 * b], q1 = idv[2 * b + 1];
        int off[8] = {q0.x, q0.y, q0.z, q0.w, q1.x, q1.y, q1.z, q1.w};
        float4 v[8];
        #pragma unroll
        for (int u = 0; u < 8; ++u)
            v[u] = *(const float4*)&bp[off[u] * 172 + dd];
        #pragma unroll
        for (int u = 0; u < 8; ++u) {
            acc.x += v[u].x; acc.y += v[u].y;
            acc.z += v[u].z; acc.w += v[u].w;
        }
    }
    acc.x *= (1.f/32.f); acc.y *= (1.f/32.f);
    acc.z *= (1.f/32.f); acc.w *= (1.f/32.f);
    *(float4*)&agg[(size_t)grow * AGG_STRIDE + (is_edge ? 172 : 0) + dd] = acc;
}

// ---------------- kernel 2: stage + time-encoding + GEMM + ReLU ----------------
__global__ __launch_bounds__(GB) void gemm_fused(
    const float* __restrict__ nodef,
    const int*   __restrict__ src_ids,
    const int*   __restrict__ dst_ids,
    const float* __restrict__ itimes,
    const int*   __restrict__ s_nbr,
    const float* __restrict__ s_t,
    const int*   __restrict__ d_nbr,
    const float* __restrict__ d_t,
    const float* __restrict__ tw,      // [100]
    const float* __restrict__ tb,      // [100]
    const float* __restrict__ W,       // [616,172]
    const float* __restrict__ bout,    // [172]
    const float* __restrict__ agg,     // [16384,344]  (ws)
    float*       __restrict__ out)     // [3,8192,172]
{
    __shared__ float inp[ROWS * PAD];
    __shared__ float dtm[ROWS * 32];
    __shared__ float msk[ROWS * 32];
    __shared__ int   curoff[ROWS];
    __shared__ float twl[100], tbl[100];

    const int tid     = threadIdx.x;
    const int side    = blockIdx.x >> 9;           // 512 blocks per side
    const int rowbase = (blockIdx.x & 511) * ROWS;

    const int*   nbr  = side ? d_nbr : s_nbr;
    const float* ntp  = side ? d_t   : s_t;
    const int*   nids = side ? dst_ids : src_ids;

    // ---- stage dt / mask (one item per thread: 16*32 == 512) ----
    {
        int i   = tid;
        int g   = rowbase * 32 + i;
        int nid = nbr[g];
        dtm[i]  = itimes[rowbase + (i >> 5)] - ntp[g];
        msk[i]  = (nid == 0) ? 0.f : 1.f;
    }
    if (tid < ROWS) curoff[tid] = nids[rowbase + tid] * 172;
    if (tid < 100) { twl[tid] = tw[tid]; tbl[tid] = tb[tid]; }
    __syncthreads();

    // ---- cur node copy (small gather): inp[r][0:172] ----
    for (int i = tid; i < ROWS * 43; i += GB) {
        int r = i / 43, c = i - r * 43;
        *(float4*)&inp[r * PAD + 4 * c] =
            *(const float4*)&nodef[curoff[r] + 4 * c];
    }

    // ---- agg copy (dense from ws): inp[r][172:516] ----
    for (int i = tid; i < ROWS * 86; i += GB) {
        int r = i / 86, c = i - r * 86;
        *(float4*)&inp[r * PAD + 172 + 4 * c] =
            *(const float4*)&agg[(size_t)(side * 8192 + rowbase + r) * AGG_STRIDE + 4 * c];
    }

    // ---- time encoding: inp[r][516+j] ----
    for (int i = tid; i < ROWS * 100; i += GB) {
        int r = i / 100, j = i - r * 100;
        const int rb = r * 32;
        float w = twl[j], b = tbl[j];
        float acc = 0.f;
        #pragma unroll
        for (int s = 0; s < 32; ++s)
            acc += msk[rb + s] * __cosf(dtm[rb + s] * w + b);
        inp[r * PAD + 516 + j] = acc * (1.f / 32.f);
    }
    __syncthreads();

    // ---- GEMM: out[16,172] = relu(inp[16,616] @ W[616,172] + b) ----
    // 344 threads = 8 row-tiles x 43 col-tiles, each thread 2 rows x 4 cols
    if (tid < 344) {
        const int ct = tid % 43, rt = tid / 43;
        const int j0 = ct * 4, r0 = rt * 2;
        float acc[2][4] = {};
        float a[2][4];
        for (int k = 0; k < 616; k += 4) {
            #pragma unroll
            for (int ri = 0; ri < 2; ++ri)
                *(float4*)&a[ri][0] = *(const float4*)&inp[(r0 + ri) * PAD + k];
            #pragma unroll
            for (int kk = 0; kk < 4; ++kk) {
                float4 wv = *(const float4*)&W[(k + kk) * 172 + j0];
                #pragma unroll
                for (int ri = 0; ri < 2; ++ri) {
                    acc[ri][0] += a[ri][kk] * wv.x;
                    acc[ri][1] += a[ri][kk] * wv.y;
                    acc[ri][2] += a[ri][kk] * wv.z;
                    acc[ri][3] += a[ri][kk] * wv.w;
                }
            }
        }
        float4 bias = *(const float4*)&bout[j0];
        #pragma unroll
        for (int ri = 0; ri < 2; ++ri) {
            int row = rowbase + r0 + ri;
            float4 v;
            v.x = fmaxf(acc[ri][0] + bias.x, 0.f);
            v.y = fmaxf(acc[ri][1] + bias.y, 0.f);
            v.z = fmaxf(acc[ri][2] + bias.z, 0.f);
            v.w = fmaxf(acc[ri][3] + bias.w, 0.f);
            *(float4*)&out[(size_t)(side * 8192 + row) * 172 + j0] = v;
        }
    }

    // ---- dummy third output = zeros (side-0 blocks) ----
    if (side == 0) {
        const float4 z = {0.f, 0.f, 0.f, 0.f};
        for (int i = tid; i < ROWS * 43; i += GB) {
            int r = i / 43, c = i - r * 43;
            *(float4*)&out[(size_t)(2 * 8192 + rowbase + r) * 172 + 4 * c] = z;
        }
    }
}

extern "C" void kernel_launch(void* const* d_in, const int* in_sizes, int n_in,
                              void* d_out, int out_size, void* d_ws, size_t ws_size,
                              hipStream_t stream) {
    const float* nodef   = (const float*)d_in[0];
    const float* edgef   = (const float*)d_in[1];
    const int*   src_ids = (const int*)  d_in[2];
    const int*   dst_ids = (const int*)  d_in[3];
    const float* itimes  = (const float*)d_in[4];
    const int*   s_nbr   = (const int*)  d_in[5];
    const int*   s_eid   = (const int*)  d_in[6];
    const float* s_t     = (const float*)d_in[7];
    const int*   d_nbr   = (const int*)  d_in[8];
    const int*   d_eid   = (const int*)  d_in[9];
    const float* d_t     = (const float*)d_in[10];
    const float* tw      = (const float*)d_in[11];
    const float* tb      = (const float*)d_in[12];
    const float* W       = (const float*)d_in[13];
    const float* bout    = (const float*)d_in[14];
    float* out = (float*)d_out;
    float* agg = (float*)d_ws;   // [16384,344] f32 = 21.5 MB

    // 16384*86 items / 256 = 5504 blocks exactly
    prep_gather<<<5504, PB, 0, stream>>>(
        nodef, edgef, s_nbr, s_eid, d_nbr, d_eid, agg);

    gemm_fused<<<1024, GB, 0, stream>>>(
        nodef, src_ids, dst_ids, itimes,
        s_nbr, s_t, d_nbr, d_t,
        tw, tb, W, bout, agg, out);
}